// Round 4
// baseline (496.860 us; speedup 1.0000x reference)
//
#include <hip/hip_runtime.h>
#include <hip/hip_bf16.h>
#include <stdint.h>

#define N_TOK 4096
#define C_DIM 1024
#define F_DIM 2048
#define E_NUM 8
#define SMAX 9216       // 72 tiles * 128 rows: max padded slot count
#define TILES_MAX 72
#define RBLK 1024       // router blocks (4 tokens each)

typedef __attribute__((ext_vector_type(4))) float f32x4;
typedef __attribute__((ext_vector_type(8))) short s16x8;

__device__ __forceinline__ uint16_t f2bf(float f) {
    unsigned x;
    __builtin_memcpy(&x, &f, 4);
    unsigned r = (x + 0x7fffu + ((x >> 16) & 1u)) >> 16;  // RNE
    return (uint16_t)r;
}

#define GLL16(gp, lp)                                                                  \
    __builtin_amdgcn_global_load_lds((const __attribute__((address_space(1))) unsigned int*)(gp), \
                                     (__attribute__((address_space(3))) unsigned int*)(lp), 16, 0, 0)

// ---------------- router: fp32 logits -> softmax -> top2; LDS-aggregated partials ----------------
__global__ void router_kernel(const float* __restrict__ x, const float* __restrict__ rw,
                              int* __restrict__ topk_idx, float* __restrict__ topk_w,
                              float* __restrict__ psum_part, int* __restrict__ cnt_part) {
    __shared__ float s_p[E_NUM];
    __shared__ int s_c[E_NUM];
    if (threadIdx.x < E_NUM) { s_p[threadIdx.x] = 0.f; s_c[threadIdx.x] = 0; }
    __syncthreads();

    int lane = threadIdx.x & 63;
    int wv = threadIdx.x >> 6;
    int t = blockIdx.x * 4 + wv;

    const float* xr = x + (size_t)t * C_DIM + lane * 16;
    float xs[16];
    for (int i = 0; i < 4; i++) *(float4*)&xs[i * 4] = *(const float4*)(xr + i * 4);

    float acc[E_NUM];
    for (int e = 0; e < E_NUM; e++) {
        const float* wr = rw + e * C_DIM + lane * 16;
        float s = 0.f;
        for (int i = 0; i < 4; i++) {
            float4 v = *(const float4*)(wr + i * 4);
            s += xs[i * 4] * v.x + xs[i * 4 + 1] * v.y + xs[i * 4 + 2] * v.z + xs[i * 4 + 3] * v.w;
        }
        acc[e] = s;
    }
    for (int off = 32; off > 0; off >>= 1)
        for (int e = 0; e < E_NUM; e++) acc[e] += __shfl_down(acc[e], off, 64);

    if (lane == 0) {
        float m = acc[0];
        for (int e = 1; e < E_NUM; e++) m = fmaxf(m, acc[e]);
        float p[E_NUM], s = 0.f;
        for (int e = 0; e < E_NUM; e++) { p[e] = __expf(acc[e] - m); s += p[e]; }
        float inv = 1.f / s;
        for (int e = 0; e < E_NUM; e++) { p[e] *= inv; atomicAdd(&s_p[e], p[e]); }  // LDS atomic
        int i0 = 0;
        for (int e = 1; e < E_NUM; e++) if (p[e] > p[i0]) i0 = e;         // ties -> lowest idx
        int i1 = (i0 == 0) ? 1 : 0;
        for (int e = 0; e < E_NUM; e++) if (e != i0 && p[e] > p[i1]) i1 = e;
        float w0 = p[i0], w1 = p[i1], wsum = w0 + w1;
        topk_idx[t * 2] = i0; topk_idx[t * 2 + 1] = i1;
        topk_w[t * 2] = w0 / wsum; topk_w[t * 2 + 1] = w1 / wsum;
        atomicAdd(&s_c[i0], 1); atomicAdd(&s_c[i1], 1);                   // LDS atomic
    }
    __syncthreads();
    if (threadIdx.x < E_NUM) {
        psum_part[blockIdx.x * E_NUM + threadIdx.x] = s_p[threadIdx.x];
        cnt_part[blockIdx.x * E_NUM + threadIdx.x] = s_c[threadIdx.x];
    }
}

// ---------------- reduce partials -> counts/psum; plan offsets+tiles; aux loss ----------------
__global__ void reduce_plan_kernel(const float* __restrict__ psum_part, const int* __restrict__ cnt_part,
                                   int* __restrict__ offsets, int* __restrict__ tile_expert,
                                   int* __restrict__ tile_row0, float* __restrict__ aux_out) {
    __shared__ float sp[256];
    __shared__ int sc[256];
    __shared__ int s_count[E_NUM];
    __shared__ float s_psum[E_NUM];
    int e = threadIdx.x >> 5, i = threadIdx.x & 31;
    float fp = 0.f; int c = 0;
    for (int j = i; j < RBLK; j += 32) { fp += psum_part[j * E_NUM + e]; c += cnt_part[j * E_NUM + e]; }
    sp[threadIdx.x] = fp; sc[threadIdx.x] = c;
    __syncthreads();
    for (int s = 16; s > 0; s >>= 1) {
        if (i < s) { sp[threadIdx.x] += sp[threadIdx.x + s]; sc[threadIdx.x] += sc[threadIdx.x + s]; }
        __syncthreads();
    }
    if (i == 0) { s_count[e] = sc[threadIdx.x]; s_psum[e] = sp[threadIdx.x]; }
    __syncthreads();
    if (threadIdx.x == 0) {
        int off = 0, t = 0;
        for (int ee = 0; ee < E_NUM; ee++) {
            offsets[ee] = off;
            int n = s_count[ee];
            int nt = (n + 127) >> 7;
            for (int k = 0; k < nt; k++) { tile_expert[t] = ee; tile_row0[t] = off + k * 128; t++; }
            off += nt * 128;
        }
        offsets[E_NUM] = off;
        for (; t < TILES_MAX; t++) tile_expert[t] = -1;
        float s = 0.f;
        for (int ee = 0; ee < E_NUM; ee++) { float a = s_psum[ee] * (1.f / N_TOK); s += a * a; }
        aux_out[0] = 8.f * s;
    }
}

// ---------------- assign: block-aggregated slot reservation ----------------
__global__ void assign_kernel(const int* __restrict__ topk_idx, const float* __restrict__ topk_w,
                              const int* __restrict__ offsets, int* __restrict__ count2,
                              int* __restrict__ slot_map, float* __restrict__ slot_w) {
    __shared__ int h[E_NUM];
    __shared__ int base[E_NUM];
    if (threadIdx.x < E_NUM) h[threadIdx.x] = 0;
    __syncthreads();
    int item = blockIdx.x * 256 + threadIdx.x;
    int e = topk_idx[item];
    int rank = atomicAdd(&h[e], 1);         // LDS atomic
    __syncthreads();
    if (threadIdx.x < E_NUM)
        base[threadIdx.x] = offsets[threadIdx.x] + atomicAdd(&count2[threadIdx.x], h[threadIdx.x]);
    __syncthreads();
    int slot = base[e] + rank;
    slot_map[slot] = item;
    slot_w[slot] = topk_w[item];
}

// ---------------- gather: copy+convert x rows (fp32 -> bf16) into slot space ----------------
__global__ void gather_kernel(const float* __restrict__ x, const int* __restrict__ slot_map,
                              uint16_t* __restrict__ x_slots) {
    int slot = blockIdx.x;
    int item = slot_map[slot];
    if (item < 0) return;  // padding row: leave poison (tiny denormals, harmless)
    int t = item >> 1;
    float4 v = *(const float4*)(x + (size_t)t * C_DIM + threadIdx.x * 4);
    union { uint16_t u[4]; uint2 q; } r;
    r.u[0] = f2bf(v.x); r.u[1] = f2bf(v.y); r.u[2] = f2bf(v.z); r.u[3] = f2bf(v.w);
    *(uint2*)(x_slots + (size_t)slot * C_DIM + threadIdx.x * 4) = r.q;
}

// ---------------- convert+transpose fp32 [R][Cc] -> bf16 [Cc][R]; 64c x 128r tiles ----------------
// phase1: float4 coalesced reads -> LDS bf16 (row stride 66 elems: 2-way max conflicts)
// phase2: each thread packs 32 consecutive R values of one output row -> 64B contiguous store
__global__ __launch_bounds__(256) void convT_kernel(const float* __restrict__ in,
                                                    uint16_t* __restrict__ out, int R, int Cc) {
    __shared__ uint16_t s[128 * 66];
    size_t zb = (size_t)blockIdx.z * (size_t)R * Cc;
    int c0 = blockIdx.x * 64, r0 = blockIdx.y * 128;
    int cx = (threadIdx.x & 15) * 4, ry = threadIdx.x >> 4;
    for (int j = 0; j < 8; j++) {
        int r = ry + j * 16;
        float4 v = *(const float4*)(in + zb + (size_t)(r0 + r) * Cc + c0 + cx);
        uint16_t* p = &s[r * 66 + cx];
        p[0] = f2bf(v.x); p[1] = f2bf(v.y); p[2] = f2bf(v.z); p[3] = f2bf(v.w);
    }
    __syncthreads();
    int oc = threadIdx.x & 63, wseg = threadIdx.x >> 6;  // 4 waves, 32 rows each
    uint16_t tmp[32];
    for (int j = 0; j < 32; j++) tmp[j] = s[(wseg * 32 + j) * 66 + oc];
    uint4* dst = (uint4*)(out + zb + (size_t)(c0 + oc) * R + r0 + wseg * 32);
    dst[0] = *(const uint4*)&tmp[0];
    dst[1] = *(const uint4*)&tmp[8];
    dst[2] = *(const uint4*)&tmp[16];
    dst[3] = *(const uint4*)&tmp[24];
}

// LDS XOR swizzle: global k-chunk q of row r lives at column slot q ^ ((r>>1)&3).
// Staging lane i (GLL dest = base + i*16, row = base_row + (i>>2)) loads global chunk
// (i&3) ^ ((i>>3)&3). Fragment read for (row=..+(lane&15), quad=lane>>4) uses slot
// (lane>>4) ^ ((lane>>1)&3). All row bases are multiples of 4 so (r>>1)&3 reduces to lane bits.

// ---------------- GEMM1: act = swiglu(x_slots @ w_v[e]) ; 128 rows x (64 gate + 64 value) ----------------
__global__ __launch_bounds__(256) void gemm1_kernel(const uint16_t* __restrict__ x_slots,
                                                    const uint16_t* __restrict__ wvT,
                                                    const int* __restrict__ tile_expert,
                                                    const int* __restrict__ tile_row0,
                                                    uint16_t* __restrict__ act) {
    int e = tile_expert[blockIdx.y];
    if (e < 0) return;
    int row0 = tile_row0[blockIdx.y];
    int j = blockIdx.x;  // 0..31, gate cols [j*64, j*64+64)
    __shared__ uint16_t As[128 * 32];
    __shared__ uint16_t Bg[64 * 32];
    __shared__ uint16_t Bv[64 * 32];
    int lane = threadIdx.x & 63, w = threadIdx.x >> 6;
    int wm = w & 1, wn = w >> 1;
    const uint16_t* wvb = wvT + (size_t)e * 4096 * 1024;  // [n=4096][k=1024]

    int sk = (((lane & 3) ^ ((lane >> 3) & 3))) * 8;   // swizzled global k-offset for staging
    int ar = w * 32 + (lane >> 2);            // A row, instr0
    const uint16_t* agp0 = x_slots + (size_t)(row0 + ar) * C_DIM + sk;
    const uint16_t* agp1 = agp0 + (size_t)16 * C_DIM;
    int br = w * 16 + (lane >> 2);            // B row (n) for this wave
    const uint16_t* bgp = wvb + (size_t)(j * 64 + br) * C_DIM + sk;
    const uint16_t* bvp = wvb + (size_t)(2048 + j * 64 + br) * C_DIM + sk;

    int cswz = ((lane >> 4) ^ ((lane >> 1) & 3)) * 8;  // swizzled LDS column for fragment reads

    f32x4 accg[4][2], accv[4][2];
    f32x4 z4 = {0.f, 0.f, 0.f, 0.f};
    for (int mf = 0; mf < 4; mf++)
        for (int nf = 0; nf < 2; nf++) { accg[mf][nf] = z4; accv[mf][nf] = z4; }

    for (int kt = 0; kt < 32; ++kt) {
        int ko = kt * 32;
        __syncthreads();
        GLL16(agp0 + ko, As + w * 1024);
        GLL16(agp1 + ko, As + w * 1024 + 512);
        GLL16(bgp + ko, Bg + w * 512);
        GLL16(bvp + ko, Bv + w * 512);
        __syncthreads();
        s16x8 af[4], bg[2], bv[2];
        for (int mf = 0; mf < 4; mf++)
            af[mf] = *(const s16x8*)&As[(wm * 64 + mf * 16 + (lane & 15)) * 32 + cswz];
        for (int nf = 0; nf < 2; nf++) {
            bg[nf] = *(const s16x8*)&Bg[(wn * 32 + nf * 16 + (lane & 15)) * 32 + cswz];
            bv[nf] = *(const s16x8*)&Bv[(wn * 32 + nf * 16 + (lane & 15)) * 32 + cswz];
        }
        for (int mf = 0; mf < 4; mf++)
            for (int nf = 0; nf < 2; nf++) {
                accg[mf][nf] = __builtin_amdgcn_mfma_f32_16x16x32_bf16(af[mf], bg[nf], accg[mf][nf], 0, 0, 0);
                accv[mf][nf] = __builtin_amdgcn_mfma_f32_16x16x32_bf16(af[mf], bv[nf], accv[mf][nf], 0, 0, 0);
            }
    }
    for (int mf = 0; mf < 4; mf++)
        for (int nf = 0; nf < 2; nf++)
            for (int r = 0; r < 4; r++) {
                int row = row0 + wm * 64 + mf * 16 + (lane >> 4) * 4 + r;
                int col = j * 64 + wn * 32 + nf * 16 + (lane & 15);
                float g = accg[mf][nf][r], v = accv[mf][nf][r];
                float a = g * v / (1.f + __expf(-g));  // silu(g)*v
                act[(size_t)row * F_DIM + col] = f2bf(a);
            }
}

// ---------------- GEMM2: out[t] += weight * (act @ c_proj[e]) ; 128x128 tile, fp32 atomics ----------------
__global__ __launch_bounds__(256) void gemm2_kernel(const uint16_t* __restrict__ act,
                                                    const uint16_t* __restrict__ cpT,
                                                    const int* __restrict__ tile_expert,
                                                    const int* __restrict__ tile_row0,
                                                    const int* __restrict__ slot_map,
                                                    const float* __restrict__ slot_w,
                                                    float* __restrict__ out) {
    int e = tile_expert[blockIdx.y];
    if (e < 0) return;
    int row0 = tile_row0[blockIdx.y];
    int cb = blockIdx.x * 128;
    __shared__ uint16_t As[128 * 32];
    __shared__ uint16_t Bs[128 * 32];
    int lane = threadIdx.x & 63, w = threadIdx.x >> 6;
    int wm = w & 1, wn = w >> 1;
    const uint16_t* cpb = cpT + (size_t)e * 1024 * 2048;  // [n=1024][k=2048]

    int sk = (((lane & 3) ^ ((lane >> 3) & 3))) * 8;
    int ar = w * 32 + (lane >> 2);
    const uint16_t* agp0 = act + (size_t)(row0 + ar) * F_DIM + sk;
    const uint16_t* agp1 = agp0 + (size_t)16 * F_DIM;
    const uint16_t* bgp0 = cpb + (size_t)(cb + ar) * F_DIM + sk;
    const uint16_t* bgp1 = bgp0 + (size_t)16 * F_DIM;

    int cswz = ((lane >> 4) ^ ((lane >> 1) & 3)) * 8;

    f32x4 acc[4][4];
    f32x4 z4 = {0.f, 0.f, 0.f, 0.f};
    for (int mf = 0; mf < 4; mf++)
        for (int nf = 0; nf < 4; nf++) acc[mf][nf] = z4;

    for (int kt = 0; kt < 64; ++kt) {
        int ko = kt * 32;
        __syncthreads();
        GLL16(agp0 + ko, As + w * 1024);
        GLL16(agp1 + ko, As + w * 1024 + 512);
        GLL16(bgp0 + ko, Bs + w * 1024);
        GLL16(bgp1 + ko, Bs + w * 1024 + 512);
        __syncthreads();
        s16x8 af[4], bf[4];
        for (int mf = 0; mf < 4; mf++)
            af[mf] = *(const s16x8*)&As[(wm * 64 + mf * 16 + (lane & 15)) * 32 + cswz];
        for (int nf = 0; nf < 4; nf++)
            bf[nf] = *(const s16x8*)&Bs[(wn * 64 + nf * 16 + (lane & 15)) * 32 + cswz];
        for (int mf = 0; mf < 4; mf++)
            for (int nf = 0; nf < 4; nf++)
                acc[mf][nf] = __builtin_amdgcn_mfma_f32_16x16x32_bf16(af[mf], bf[nf], acc[mf][nf], 0, 0, 0);
    }
    for (int mf = 0; mf < 4; mf++)
        for (int r = 0; r < 4; r++) {
            int slotr = row0 + wm * 64 + mf * 16 + (lane >> 4) * 4 + r;
            int t2k = slot_map[slotr];
            if (t2k < 0) continue;  // padding row
            float wgt = slot_w[slotr];
            int t = t2k >> 1;
            for (int nf = 0; nf < 4; nf++) {
                int col = cb + wn * 64 + nf * 16 + (lane & 15);
                atomicAdd(&out[(size_t)t * C_DIM + col], wgt * acc[mf][nf][r]);
            }
        }
}

extern "C" void kernel_launch(void* const* d_in, const int* in_sizes, int n_in,
                              void* d_out, int out_size, void* d_ws, size_t ws_size,
                              hipStream_t stream) {
    (void)in_sizes; (void)n_in; (void)out_size; (void)ws_size;
    const float* x = (const float*)d_in[0];
    const float* rw = (const float*)d_in[1];
    const float* wv = (const float*)d_in[2];
    const float* cp = (const float*)d_in[3];
    float* out = (float*)d_out;

    char* ws = (char*)d_ws;
    size_t off = 0;
    auto alloc = [&](size_t sz) -> void* {
        off = (off + 255) & ~(size_t)255;
        void* p = ws + off;
        off += sz;
        return p;
    };
    uint16_t* wvT = (uint16_t*)alloc((size_t)E_NUM * 4096 * 1024 * 2);   // 64 MB
    uint16_t* cpT = (uint16_t*)alloc((size_t)E_NUM * 1024 * 2048 * 2);   // 32 MB
    uint16_t* x_slots = (uint16_t*)alloc((size_t)SMAX * C_DIM * 2);      // ~19 MB
    uint16_t* act = (uint16_t*)alloc((size_t)SMAX * F_DIM * 2);          // ~38 MB
    float* psum_part = (float*)alloc((size_t)RBLK * E_NUM * 4);
    int* cnt_part = (int*)alloc((size_t)RBLK * E_NUM * 4);
    int* count2 = (int*)alloc(E_NUM * 4);
    int* offsets = (int*)alloc((E_NUM + 1) * 4);
    int* tile_expert = (int*)alloc(TILES_MAX * 4);
    int* tile_row0 = (int*)alloc(TILES_MAX * 4);
    int* topk_idx = (int*)alloc((size_t)N_TOK * 2 * 4);
    float* topk_w = (float*)alloc((size_t)N_TOK * 2 * 4);
    int* slot_map = (int*)alloc((size_t)SMAX * 4);
    float* slot_w = (float*)alloc((size_t)SMAX * 4);

    hipMemsetAsync(count2, 0, E_NUM * 4, stream);
    hipMemsetAsync(slot_map, 0xFF, (size_t)SMAX * 4, stream);  // -1 => padding
    hipMemsetAsync(out, 0, ((size_t)N_TOK * C_DIM + 1) * 4, stream);

    router_kernel<<<RBLK, 256, 0, stream>>>(x, rw, topk_idx, topk_w, psum_part, cnt_part);
    reduce_plan_kernel<<<1, 256, 0, stream>>>(psum_part, cnt_part, offsets, tile_expert, tile_row0,
                                              out + (size_t)N_TOK * C_DIM);
    assign_kernel<<<N_TOK * 2 / 256, 256, 0, stream>>>(topk_idx, topk_w, offsets, count2,
                                                       slot_map, slot_w);
    gather_kernel<<<SMAX, 256, 0, stream>>>(x, slot_map, x_slots);
    convT_kernel<<<dim3(4096 / 64, 1024 / 128, E_NUM), 256, 0, stream>>>(wv, wvT, 1024, 4096);
    convT_kernel<<<dim3(1024 / 64, 2048 / 128, E_NUM), 256, 0, stream>>>(cp, cpT, 2048, 1024);
    gemm1_kernel<<<dim3(32, TILES_MAX), 256, 0, stream>>>(x_slots, wvT, tile_expert, tile_row0, act);
    gemm2_kernel<<<dim3(8, TILES_MAX), 256, 0, stream>>>(act, cpT, tile_expert, tile_row0,
                                                         slot_map, slot_w, out);
}

// Round 5
// 482.782 us; speedup vs baseline: 1.0292x; 1.0292x over previous
//
#include <hip/hip_runtime.h>
#include <hip/hip_bf16.h>
#include <stdint.h>

#define N_TOK 4096
#define C_DIM 1024
#define F_DIM 2048
#define E_NUM 8
#define SMAX 9216       // 72 tiles * 128 rows: max padded slot count
#define TILES_MAX 72
#define RBLK 1024       // router blocks (4 tokens each)

typedef __attribute__((ext_vector_type(4))) float f32x4;
typedef __attribute__((ext_vector_type(8))) short s16x8;

__device__ __forceinline__ uint16_t f2bf(float f) {
    unsigned x;
    __builtin_memcpy(&x, &f, 4);
    unsigned r = (x + 0x7fffu + ((x >> 16) & 1u)) >> 16;  // RNE
    return (uint16_t)r;
}
__device__ __forceinline__ float bf2f(uint16_t u) {
    unsigned v = (unsigned)u << 16;
    float f;
    __builtin_memcpy(&f, &v, 4);
    return f;
}

#define GLL16(gp, lp)                                                                  \
    __builtin_amdgcn_global_load_lds((const __attribute__((address_space(1))) unsigned int*)(gp), \
                                     (__attribute__((address_space(3))) unsigned int*)(lp), 16, 0, 0)

// ---------------- router: fp32 logits -> softmax -> top2; LDS-aggregated partials ----------------
__global__ void router_kernel(const float* __restrict__ x, const float* __restrict__ rw,
                              int* __restrict__ topk_idx, float* __restrict__ topk_w,
                              float* __restrict__ psum_part, int* __restrict__ cnt_part) {
    __shared__ float s_p[E_NUM];
    __shared__ int s_c[E_NUM];
    if (threadIdx.x < E_NUM) { s_p[threadIdx.x] = 0.f; s_c[threadIdx.x] = 0; }
    __syncthreads();

    int lane = threadIdx.x & 63;
    int wv = threadIdx.x >> 6;
    int t = blockIdx.x * 4 + wv;

    const float* xr = x + (size_t)t * C_DIM + lane * 16;
    float xs[16];
    for (int i = 0; i < 4; i++) *(float4*)&xs[i * 4] = *(const float4*)(xr + i * 4);

    float acc[E_NUM];
    for (int e = 0; e < E_NUM; e++) {
        const float* wr = rw + e * C_DIM + lane * 16;
        float s = 0.f;
        for (int i = 0; i < 4; i++) {
            float4 v = *(const float4*)(wr + i * 4);
            s += xs[i * 4] * v.x + xs[i * 4 + 1] * v.y + xs[i * 4 + 2] * v.z + xs[i * 4 + 3] * v.w;
        }
        acc[e] = s;
    }
    for (int off = 32; off > 0; off >>= 1)
        for (int e = 0; e < E_NUM; e++) acc[e] += __shfl_down(acc[e], off, 64);

    if (lane == 0) {
        float m = acc[0];
        for (int e = 1; e < E_NUM; e++) m = fmaxf(m, acc[e]);
        float p[E_NUM], s = 0.f;
        for (int e = 0; e < E_NUM; e++) { p[e] = __expf(acc[e] - m); s += p[e]; }
        float inv = 1.f / s;
        for (int e = 0; e < E_NUM; e++) { p[e] *= inv; atomicAdd(&s_p[e], p[e]); }  // LDS atomic
        int i0 = 0;
        for (int e = 1; e < E_NUM; e++) if (p[e] > p[i0]) i0 = e;         // ties -> lowest idx
        int i1 = (i0 == 0) ? 1 : 0;
        for (int e = 0; e < E_NUM; e++) if (e != i0 && p[e] > p[i1]) i1 = e;
        float w0 = p[i0], w1 = p[i1], wsum = w0 + w1;
        topk_idx[t * 2] = i0; topk_idx[t * 2 + 1] = i1;
        topk_w[t * 2] = w0 / wsum; topk_w[t * 2 + 1] = w1 / wsum;
        atomicAdd(&s_c[i0], 1); atomicAdd(&s_c[i1], 1);                   // LDS atomic
    }
    __syncthreads();
    if (threadIdx.x < E_NUM) {
        psum_part[blockIdx.x * E_NUM + threadIdx.x] = s_p[threadIdx.x];
        cnt_part[blockIdx.x * E_NUM + threadIdx.x] = s_c[threadIdx.x];
    }
}

// ---------------- reduce partials -> counts/psum; plan offsets+tiles; aux loss ----------------
__global__ void reduce_plan_kernel(const float* __restrict__ psum_part, const int* __restrict__ cnt_part,
                                   int* __restrict__ offsets, int* __restrict__ tile_expert,
                                   int* __restrict__ tile_row0, float* __restrict__ aux_out) {
    __shared__ float sp[256];
    __shared__ int sc[256];
    __shared__ int s_count[E_NUM];
    __shared__ float s_psum[E_NUM];
    int e = threadIdx.x >> 5, i = threadIdx.x & 31;
    float fp = 0.f; int c = 0;
    for (int j = i; j < RBLK; j += 32) { fp += psum_part[j * E_NUM + e]; c += cnt_part[j * E_NUM + e]; }
    sp[threadIdx.x] = fp; sc[threadIdx.x] = c;
    __syncthreads();
    for (int s = 16; s > 0; s >>= 1) {
        if (i < s) { sp[threadIdx.x] += sp[threadIdx.x + s]; sc[threadIdx.x] += sc[threadIdx.x + s]; }
        __syncthreads();
    }
    if (i == 0) { s_count[e] = sc[threadIdx.x]; s_psum[e] = sp[threadIdx.x]; }
    __syncthreads();
    if (threadIdx.x == 0) {
        int off = 0, t = 0;
        for (int ee = 0; ee < E_NUM; ee++) {
            offsets[ee] = off;
            int n = s_count[ee];
            int nt = (n + 127) >> 7;
            for (int k = 0; k < nt; k++) { tile_expert[t] = ee; tile_row0[t] = off + k * 128; t++; }
            off += nt * 128;
        }
        offsets[E_NUM] = off;
        for (; t < TILES_MAX; t++) tile_expert[t] = -1;
        float s = 0.f;
        for (int ee = 0; ee < E_NUM; ee++) { float a = s_psum[ee] * (1.f / N_TOK); s += a * a; }
        aux_out[0] = 8.f * s;
    }
}

// ---------------- assign: block-aggregated slot reservation + inverse map ----------------
__global__ void assign_kernel(const int* __restrict__ topk_idx, const float* __restrict__ topk_w,
                              const int* __restrict__ offsets, int* __restrict__ count2,
                              int* __restrict__ slot_map, float* __restrict__ slot_w,
                              int* __restrict__ tok_slot) {
    __shared__ int h[E_NUM];
    __shared__ int base[E_NUM];
    if (threadIdx.x < E_NUM) h[threadIdx.x] = 0;
    __syncthreads();
    int item = blockIdx.x * 256 + threadIdx.x;
    int e = topk_idx[item];
    int rank = atomicAdd(&h[e], 1);         // LDS atomic
    __syncthreads();
    if (threadIdx.x < E_NUM)
        base[threadIdx.x] = offsets[threadIdx.x] + atomicAdd(&count2[threadIdx.x], h[threadIdx.x]);
    __syncthreads();
    int slot = base[e] + rank;
    slot_map[slot] = item;
    slot_w[slot] = topk_w[item];
    tok_slot[item] = slot;
}

// ---------------- gather: copy+convert x rows (fp32 -> bf16) into slot space ----------------
__global__ void gather_kernel(const float* __restrict__ x, const int* __restrict__ slot_map,
                              uint16_t* __restrict__ x_slots) {
    int slot = blockIdx.x;
    int item = slot_map[slot];
    if (item < 0) return;  // padding row: leave poison (tiny denormals, harmless)
    int t = item >> 1;
    float4 v = *(const float4*)(x + (size_t)t * C_DIM + threadIdx.x * 4);
    union { uint16_t u[4]; uint2 q; } r;
    r.u[0] = f2bf(v.x); r.u[1] = f2bf(v.y); r.u[2] = f2bf(v.z); r.u[3] = f2bf(v.w);
    *(uint2*)(x_slots + (size_t)slot * C_DIM + threadIdx.x * 4) = r.q;
}

// ---------------- convert+transpose fp32 [R][Cc] -> bf16 [Cc][R]; 64c x 128r tiles ----------------
__global__ __launch_bounds__(256) void convT_kernel(const float* __restrict__ in,
                                                    uint16_t* __restrict__ out, int R, int Cc) {
    __shared__ uint16_t s[128 * 66];
    size_t zb = (size_t)blockIdx.z * (size_t)R * Cc;
    int c0 = blockIdx.x * 64, r0 = blockIdx.y * 128;
    int cx = (threadIdx.x & 15) * 4, ry = threadIdx.x >> 4;
    for (int j = 0; j < 8; j++) {
        int r = ry + j * 16;
        float4 v = *(const float4*)(in + zb + (size_t)(r0 + r) * Cc + c0 + cx);
        uint16_t* p = &s[r * 66 + cx];
        p[0] = f2bf(v.x); p[1] = f2bf(v.y); p[2] = f2bf(v.z); p[3] = f2bf(v.w);
    }
    __syncthreads();
    int oc = threadIdx.x & 63, wseg = threadIdx.x >> 6;  // 4 waves, 32 rows each
    uint16_t tmp[32];
    for (int j = 0; j < 32; j++) tmp[j] = s[(wseg * 32 + j) * 66 + oc];
    uint4* dst = (uint4*)(out + zb + (size_t)(c0 + oc) * R + r0 + wseg * 32);
    dst[0] = *(const uint4*)&tmp[0];
    dst[1] = *(const uint4*)&tmp[8];
    dst[2] = *(const uint4*)&tmp[16];
    dst[3] = *(const uint4*)&tmp[24];
}

// LDS XOR swizzle (see round-3 note): staging lane uses global chunk (i&3)^((i>>3)&3);
// fragment reads use slot (lane>>4)^((lane>>1)&3). Conflict-free (verified: SQ_LDS_BANK_CONFLICT=0).

// ---------------- GEMM1: act = swiglu(x_slots @ w_v[e]) ; 128 rows x (64 gate + 64 value) ----------------
__global__ __launch_bounds__(256) void gemm1_kernel(const uint16_t* __restrict__ x_slots,
                                                    const uint16_t* __restrict__ wvT,
                                                    const int* __restrict__ tile_expert,
                                                    const int* __restrict__ tile_row0,
                                                    uint16_t* __restrict__ act) {
    int e = tile_expert[blockIdx.y];
    if (e < 0) return;
    int row0 = tile_row0[blockIdx.y];
    int j = blockIdx.x;  // 0..31, gate cols [j*64, j*64+64)
    __shared__ uint16_t As[128 * 32];
    __shared__ uint16_t Bg[64 * 32];
    __shared__ uint16_t Bv[64 * 32];
    int lane = threadIdx.x & 63, w = threadIdx.x >> 6;
    int wm = w & 1, wn = w >> 1;
    const uint16_t* wvb = wvT + (size_t)e * 4096 * 1024;  // [n=4096][k=1024]

    int sk = (((lane & 3) ^ ((lane >> 3) & 3))) * 8;   // swizzled global k-offset for staging
    int ar = w * 32 + (lane >> 2);            // A row, instr0
    const uint16_t* agp0 = x_slots + (size_t)(row0 + ar) * C_DIM + sk;
    const uint16_t* agp1 = agp0 + (size_t)16 * C_DIM;
    int br = w * 16 + (lane >> 2);            // B row (n) for this wave
    const uint16_t* bgp = wvb + (size_t)(j * 64 + br) * C_DIM + sk;
    const uint16_t* bvp = wvb + (size_t)(2048 + j * 64 + br) * C_DIM + sk;

    int cswz = ((lane >> 4) ^ ((lane >> 1) & 3)) * 8;  // swizzled LDS column for fragment reads

    f32x4 accg[4][2], accv[4][2];
    f32x4 z4 = {0.f, 0.f, 0.f, 0.f};
    for (int mf = 0; mf < 4; mf++)
        for (int nf = 0; nf < 2; nf++) { accg[mf][nf] = z4; accv[mf][nf] = z4; }

    for (int kt = 0; kt < 32; ++kt) {
        int ko = kt * 32;
        __syncthreads();
        GLL16(agp0 + ko, As + w * 1024);
        GLL16(agp1 + ko, As + w * 1024 + 512);
        GLL16(bgp + ko, Bg + w * 512);
        GLL16(bvp + ko, Bv + w * 512);
        __syncthreads();
        s16x8 af[4], bg[2], bv[2];
        for (int mf = 0; mf < 4; mf++)
            af[mf] = *(const s16x8*)&As[(wm * 64 + mf * 16 + (lane & 15)) * 32 + cswz];
        for (int nf = 0; nf < 2; nf++) {
            bg[nf] = *(const s16x8*)&Bg[(wn * 32 + nf * 16 + (lane & 15)) * 32 + cswz];
            bv[nf] = *(const s16x8*)&Bv[(wn * 32 + nf * 16 + (lane & 15)) * 32 + cswz];
        }
        for (int mf = 0; mf < 4; mf++)
            for (int nf = 0; nf < 2; nf++) {
                accg[mf][nf] = __builtin_amdgcn_mfma_f32_16x16x32_bf16(af[mf], bg[nf], accg[mf][nf], 0, 0, 0);
                accv[mf][nf] = __builtin_amdgcn_mfma_f32_16x16x32_bf16(af[mf], bv[nf], accv[mf][nf], 0, 0, 0);
            }
    }
    for (int mf = 0; mf < 4; mf++)
        for (int nf = 0; nf < 2; nf++)
            for (int r = 0; r < 4; r++) {
                int row = row0 + wm * 64 + mf * 16 + (lane >> 4) * 4 + r;
                int col = j * 64 + wn * 32 + nf * 16 + (lane & 15);
                float g = accg[mf][nf][r], v = accv[mf][nf][r];
                float a = g * v / (1.f + __expf(-g));  // silu(g)*v
                act[(size_t)row * F_DIM + col] = f2bf(a);
            }
}

// ---------------- GEMM2: eo[slot] = weight * (act @ c_proj[e]) ; 128x128 tile, PLAIN bf16 stores ----------------
__global__ __launch_bounds__(256) void gemm2_kernel(const uint16_t* __restrict__ act,
                                                    const uint16_t* __restrict__ cpT,
                                                    const int* __restrict__ tile_expert,
                                                    const int* __restrict__ tile_row0,
                                                    const int* __restrict__ slot_map,
                                                    const float* __restrict__ slot_w,
                                                    uint16_t* __restrict__ eo) {
    int e = tile_expert[blockIdx.y];
    if (e < 0) return;
    int row0 = tile_row0[blockIdx.y];
    int cb = blockIdx.x * 128;
    __shared__ uint16_t As[128 * 32];
    __shared__ uint16_t Bs[128 * 32];
    int lane = threadIdx.x & 63, w = threadIdx.x >> 6;
    int wm = w & 1, wn = w >> 1;
    const uint16_t* cpb = cpT + (size_t)e * 1024 * 2048;  // [n=1024][k=2048]

    int sk = (((lane & 3) ^ ((lane >> 3) & 3))) * 8;
    int ar = w * 32 + (lane >> 2);
    const uint16_t* agp0 = act + (size_t)(row0 + ar) * F_DIM + sk;
    const uint16_t* agp1 = agp0 + (size_t)16 * F_DIM;
    const uint16_t* bgp0 = cpb + (size_t)(cb + ar) * F_DIM + sk;
    const uint16_t* bgp1 = bgp0 + (size_t)16 * F_DIM;

    int cswz = ((lane >> 4) ^ ((lane >> 1) & 3)) * 8;

    f32x4 acc[4][4];
    f32x4 z4 = {0.f, 0.f, 0.f, 0.f};
    for (int mf = 0; mf < 4; mf++)
        for (int nf = 0; nf < 4; nf++) acc[mf][nf] = z4;

    for (int kt = 0; kt < 64; ++kt) {
        int ko = kt * 32;
        __syncthreads();
        GLL16(agp0 + ko, As + w * 1024);
        GLL16(agp1 + ko, As + w * 1024 + 512);
        GLL16(bgp0 + ko, Bs + w * 1024);
        GLL16(bgp1 + ko, Bs + w * 1024 + 512);
        __syncthreads();
        s16x8 af[4], bf[4];
        for (int mf = 0; mf < 4; mf++)
            af[mf] = *(const s16x8*)&As[(wm * 64 + mf * 16 + (lane & 15)) * 32 + cswz];
        for (int nf = 0; nf < 4; nf++)
            bf[nf] = *(const s16x8*)&Bs[(wn * 64 + nf * 16 + (lane & 15)) * 32 + cswz];
        for (int mf = 0; mf < 4; mf++)
            for (int nf = 0; nf < 4; nf++)
                acc[mf][nf] = __builtin_amdgcn_mfma_f32_16x16x32_bf16(af[mf], bf[nf], acc[mf][nf], 0, 0, 0);
    }
    for (int mf = 0; mf < 4; mf++)
        for (int r = 0; r < 4; r++) {
            int slotr = row0 + wm * 64 + mf * 16 + (lane >> 4) * 4 + r;
            int t2k = slot_map[slotr];
            if (t2k < 0) continue;  // padding row: skip (eo row never read)
            float wgt = slot_w[slotr];
            for (int nf = 0; nf < 4; nf++) {
                int col = cb + wn * 64 + nf * 16 + (lane & 15);
                eo[(size_t)slotr * C_DIM + col] = f2bf(wgt * acc[mf][nf][r]);
            }
        }
}

// ---------------- combine: out[t] = eo[slot0] + eo[slot1] (weights pre-applied) ----------------
__global__ void combine_kernel(const uint16_t* __restrict__ eo, const int* __restrict__ tok_slot,
                               float* __restrict__ out) {
    int t = blockIdx.x;
    int s0 = tok_slot[2 * t], s1 = tok_slot[2 * t + 1];
    int c = threadIdx.x * 4;
    uint2 a = *(const uint2*)(eo + (size_t)s0 * C_DIM + c);
    uint2 b = *(const uint2*)(eo + (size_t)s1 * C_DIM + c);
    float4 o;
    o.x = bf2f((uint16_t)(a.x & 0xffff)) + bf2f((uint16_t)(b.x & 0xffff));
    o.y = bf2f((uint16_t)(a.x >> 16)) + bf2f((uint16_t)(b.x >> 16));
    o.z = bf2f((uint16_t)(a.y & 0xffff)) + bf2f((uint16_t)(b.y & 0xffff));
    o.w = bf2f((uint16_t)(a.y >> 16)) + bf2f((uint16_t)(b.y >> 16));
    *(float4*)(out + (size_t)t * C_DIM + c) = o;
}

extern "C" void kernel_launch(void* const* d_in, const int* in_sizes, int n_in,
                              void* d_out, int out_size, void* d_ws, size_t ws_size,
                              hipStream_t stream) {
    (void)in_sizes; (void)n_in; (void)out_size; (void)ws_size;
    const float* x = (const float*)d_in[0];
    const float* rw = (const float*)d_in[1];
    const float* wv = (const float*)d_in[2];
    const float* cp = (const float*)d_in[3];
    float* out = (float*)d_out;

    char* ws = (char*)d_ws;
    size_t off = 0;
    auto alloc = [&](size_t sz) -> void* {
        off = (off + 255) & ~(size_t)255;
        void* p = ws + off;
        off += sz;
        return p;
    };
    uint16_t* wvT = (uint16_t*)alloc((size_t)E_NUM * 4096 * 1024 * 2);   // 64 MB
    uint16_t* cpT = (uint16_t*)alloc((size_t)E_NUM * 1024 * 2048 * 2);   // 32 MB
    uint16_t* x_slots = (uint16_t*)alloc((size_t)SMAX * C_DIM * 2);      // ~19 MB
    uint16_t* act = (uint16_t*)alloc((size_t)SMAX * F_DIM * 2);          // ~38 MB
    uint16_t* eo = (uint16_t*)alloc((size_t)SMAX * C_DIM * 2);           // ~19 MB
    float* psum_part = (float*)alloc((size_t)RBLK * E_NUM * 4);
    int* cnt_part = (int*)alloc((size_t)RBLK * E_NUM * 4);
    int* count2 = (int*)alloc(E_NUM * 4);
    int* offsets = (int*)alloc((E_NUM + 1) * 4);
    int* tile_expert = (int*)alloc(TILES_MAX * 4);
    int* tile_row0 = (int*)alloc(TILES_MAX * 4);
    int* topk_idx = (int*)alloc((size_t)N_TOK * 2 * 4);
    float* topk_w = (float*)alloc((size_t)N_TOK * 2 * 4);
    int* slot_map = (int*)alloc((size_t)SMAX * 4);
    float* slot_w = (float*)alloc((size_t)SMAX * 4);
    int* tok_slot = (int*)alloc((size_t)N_TOK * 2 * 4);

    hipMemsetAsync(count2, 0, E_NUM * 4, stream);
    hipMemsetAsync(slot_map, 0xFF, (size_t)SMAX * 4, stream);  // -1 => padding

    router_kernel<<<RBLK, 256, 0, stream>>>(x, rw, topk_idx, topk_w, psum_part, cnt_part);
    reduce_plan_kernel<<<1, 256, 0, stream>>>(psum_part, cnt_part, offsets, tile_expert, tile_row0,
                                              out + (size_t)N_TOK * C_DIM);
    assign_kernel<<<N_TOK * 2 / 256, 256, 0, stream>>>(topk_idx, topk_w, offsets, count2,
                                                       slot_map, slot_w, tok_slot);
    gather_kernel<<<SMAX, 256, 0, stream>>>(x, slot_map, x_slots);
    convT_kernel<<<dim3(4096 / 64, 1024 / 128, E_NUM), 256, 0, stream>>>(wv, wvT, 1024, 4096);
    convT_kernel<<<dim3(1024 / 64, 2048 / 128, E_NUM), 256, 0, stream>>>(cp, cpT, 2048, 1024);
    gemm1_kernel<<<dim3(32, TILES_MAX), 256, 0, stream>>>(x_slots, wvT, tile_expert, tile_row0, act);
    gemm2_kernel<<<dim3(8, TILES_MAX), 256, 0, stream>>>(act, cpT, tile_expert, tile_row0,
                                                         slot_map, slot_w, eo);
    combine_kernel<<<N_TOK, 256, 0, stream>>>(eo, tok_slot, out);
}